// Round 1
// baseline (398.322 us; speedup 1.0000x reference)
//
#include <hip/hip_runtime.h>

// Per-sample 3x3 conv, NHWC, SAME padding.
// x: (32,128,128,32) f32; params: (32, 9216+32) f32 (W as [3][3][32][32] + bias[32])
// out: (32,128,128,32) f32
//
// Strategy: direct conv, register-blocked. Block = 256 threads covers a
// 16x64 spatial tile of one batch sample; each thread computes 4 adjacent
// pixels x all 32 output channels (acc[4][32] = 128 VGPRs).
// Weights are block-uniform -> scalar loads (s_load) + v_fma_f32 with SGPR
// operand: no LDS traffic at all for the weight broadcast.

constexpr int KHC = 3, KWC = 3, CINC = 32, FC = 32, HWD = 128;
constexpr int WSZ = KHC * KWC * CINC * FC;   // 9216
constexpr int PSTRIDE = WSZ + FC;            // 9248

__global__ __launch_bounds__(256, 2) void conv3x3_kernel(
    const float* __restrict__ x, const float* __restrict__ params,
    float* __restrict__ out)
{
    const int b      = blockIdx.z;
    const int tile_y = blockIdx.y;   // 0..7  (16 rows each)
    const int tile_x = blockIdx.x;   // 0..1  (64 cols each)

    const int t  = threadIdx.x;
    const int r  = t >> 4;           // 0..15 row within tile
    const int cg = t & 15;           // 0..15 col-group (4 px each)
    const int oy = tile_y * 16 + r;
    const int ox = tile_x * 64 + cg * 4;

    const float* __restrict__ pb = params + (size_t)b * PSTRIDE;
    const float* __restrict__ xb = x + (size_t)b * (HWD * HWD * CINC);

    // init accumulators with bias (scalar loads, broadcast)
    float acc[4][FC];
    #pragma unroll
    for (int f = 0; f < FC; ++f) {
        const float bias = pb[WSZ + f];
        #pragma unroll
        for (int p = 0; p < 4; ++p) acc[p][f] = bias;
    }

    for (int kh = 0; kh < 3; ++kh) {
        const int iy = oy + kh - 1;
        if (iy < 0 || iy >= HWD) continue;     // zero-padding == skip accumulation
        const float* __restrict__ xrow = xb + (size_t)iy * (HWD * CINC);
        const float* __restrict__ wkh  = pb + kh * (KWC * CINC * FC);

        for (int ci0 = 0; ci0 < CINC; ci0 += 4) {
            // load 6 columns (ox-1 .. ox+4), 4 input channels each
            float xv[6][4];
            #pragma unroll
            for (int j = 0; j < 6; ++j) {
                const int c = ox - 1 + j;
                if (c >= 0 && c < HWD) {
                    const float4 tmp = *(const float4*)(xrow + c * CINC + ci0);
                    xv[j][0] = tmp.x; xv[j][1] = tmp.y; xv[j][2] = tmp.z; xv[j][3] = tmp.w;
                } else {
                    xv[j][0] = 0.f; xv[j][1] = 0.f; xv[j][2] = 0.f; xv[j][3] = 0.f;
                }
            }
            #pragma unroll
            for (int kw = 0; kw < 3; ++kw) {
                #pragma unroll
                for (int cn = 0; cn < 4; ++cn) {
                    // wave-uniform weight pointer -> s_load into SGPRs
                    const float* __restrict__ wp = wkh + (kw * CINC + (ci0 + cn)) * FC;
                    #pragma unroll
                    for (int p = 0; p < 4; ++p) {
                        const float xs = xv[kw + p][cn];
                        #pragma unroll
                        for (int f = 0; f < FC; ++f)
                            acc[p][f] = fmaf(xs, wp[f], acc[p][f]);
                    }
                }
            }
        }
    }

    float* __restrict__ ob = out + (((size_t)(b * HWD + oy)) * HWD + ox) * FC;
    #pragma unroll
    for (int p = 0; p < 4; ++p) {
        #pragma unroll
        for (int f0 = 0; f0 < FC; f0 += 4) {
            float4 v;
            v.x = acc[p][f0 + 0];
            v.y = acc[p][f0 + 1];
            v.z = acc[p][f0 + 2];
            v.w = acc[p][f0 + 3];
            *(float4*)(ob + p * FC + f0) = v;
        }
    }
}

extern "C" void kernel_launch(void* const* d_in, const int* in_sizes, int n_in,
                              void* d_out, int out_size, void* d_ws, size_t ws_size,
                              hipStream_t stream)
{
    const float* x      = (const float*)d_in[0];
    const float* params = (const float*)d_in[1];
    float*       out    = (float*)d_out;

    dim3 grid(2, 8, 32);   // tiles_x, tiles_y, batch
    dim3 block(256);
    hipLaunchKernelGGL(conv3x3_kernel, grid, block, 0, stream, x, params, out);
}

// Round 2
// 126.038 us; speedup vs baseline: 3.1603x; 3.1603x over previous
//
#include <hip/hip_runtime.h>

// Per-sample 3x3 conv as bf16 implicit GEMM, NHWC, SAME padding.
// x: (32,128,128,32) f32; params: (32, 9216+32) f32; out: (32,128,128,32) f32
// Per sample: GEMM M=16384 px, N=32 f, K=288=(kh,kw,ci).
// Block = 2 output rows x 128 cols of one sample; 4 waves; wave = 64 px.
// MFMA: v_mfma_f32_16x16x32_bf16. A=x (im2col from LDS), B^T=W^T (LDS).

typedef __attribute__((ext_vector_type(8))) short bf16x8;
typedef __attribute__((ext_vector_type(4))) float f32x4;

constexpr int HWD  = 128, CINC = 32, FC = 32;
constexpr int WSZ  = 9 * CINC * FC;         // 9216
constexpr int PSTR = WSZ + FC;              // 9248
// LDS: xs[cig=4][row=4][col=130][8ci as 16B]  then  wt[kgrp=36][f=32][8k as 16B]
constexpr int XS_BYTES = 4 * 4 * 130 * 16;  // 33280
constexpr int WT_BYTES = 36 * 32 * 16;      // 18432
constexpr int SMEM_BYTES = XS_BYTES + WT_BYTES; // 51712 -> 3 blocks/CU

__device__ __forceinline__ int xs_off(int cig, int r, int col) {
    return ((cig * 4 + r) * 130 + col) * 16;
}
__device__ __forceinline__ int wt_off(int kgrp, int f) {
    return XS_BYTES + (kgrp * 32 + f) * 16;
}

__device__ __forceinline__ unsigned short f2bf(float f) {
    unsigned u = __float_as_uint(f);
    return (unsigned short)((u + 0x7FFFu + ((u >> 16) & 1u)) >> 16);  // RNE
}
__device__ __forceinline__ bf16x8 pack8(float4 a, float4 b) {
    bf16x8 r;
    r[0] = (short)f2bf(a.x); r[1] = (short)f2bf(a.y);
    r[2] = (short)f2bf(a.z); r[3] = (short)f2bf(a.w);
    r[4] = (short)f2bf(b.x); r[5] = (short)f2bf(b.y);
    r[6] = (short)f2bf(b.z); r[7] = (short)f2bf(b.w);
    return r;
}

__global__ __launch_bounds__(256) void conv3x3_mfma(
    const float* __restrict__ x, const float* __restrict__ params,
    float* __restrict__ out)
{
    __shared__ __align__(16) unsigned char smem[SMEM_BYTES];

    // XCD-bijective swizzle: 2048 blocks, 8 XCDs -> 256 consecutive logical
    // blocks per XCD (adjacent row-pairs of a sample share halo rows in L2).
    const int hw      = blockIdx.x;                 // 0..2047
    const int logical = (hw & 7) * 256 + (hw >> 3); // bijective (2048 % 8 == 0)
    const int b       = logical >> 6;               // sample 0..31
    const int rowpair = logical & 63;               // 0..63
    const int y0      = rowpair * 2;

    const int t = threadIdx.x;
    const float* __restrict__ xb = x + (size_t)b * (HWD * HWD * CINC);
    const float* __restrict__ pw = params + (size_t)b * PSTR;

    // ---- zero-fill xs (covers SAME padding: cols 0/129 and out-of-range rows)
    for (int i = t; i < 4 * 4 * 130; i += 256) {
        bf16x8 z = 0;
        *(bf16x8*)(smem + i * 16) = z;
    }
    __syncthreads();

    // ---- stage x rows y0-1..y0+2 as bf16, layout [cig][row][col+1][8ci]
    #pragma unroll
    for (int i = 0; i < 8; ++i) {
        const int c   = t + i * 256;     // 0..2047
        const int r   = c >> 9;          // 0..3 (lds row)
        const int rem = c & 511;
        const int col = rem >> 2;        // 0..127
        const int cig = rem & 3;
        const int iy  = y0 - 1 + r;
        if (iy >= 0 && iy < HWD) {
            const float* p = xb + ((size_t)iy * HWD + col) * CINC + cig * 8;
            const float4 v0 = *(const float4*)(p);
            const float4 v1 = *(const float4*)(p + 4);
            *(bf16x8*)(smem + xs_off(cig, r, col + 1)) = pack8(v0, v1);
        }
    }

    // ---- stage W^T as bf16: wt[kgrp][f][klo] = W[k=kgrp*8+klo][f]
    #pragma unroll
    for (int j = 0; j < 5; ++j) {
        const int c    = t + j * 256;    // 0..1279
        const int kgrp = c >> 5;         // 0..39
        const int f    = c & 31;
        if (kgrp < 36) {
            const float* p = pw + (size_t)(kgrp * 8) * FC + f;
            float4 a, bb;
            a.x  = p[0 * FC]; a.y  = p[1 * FC]; a.z  = p[2 * FC]; a.w  = p[3 * FC];
            bb.x = p[4 * FC]; bb.y = p[5 * FC]; bb.z = p[6 * FC]; bb.w = p[7 * FC];
            *(bf16x8*)(smem + wt_off(kgrp, f)) = pack8(a, bb);
        }
    }
    __syncthreads();

    // ---- main loop: wave -> 64 px (4 M-tiles of 16) x 32 f (2 N-tiles)
    const int wv   = t >> 6;          // 0..3
    const int ln   = t & 63;
    const int lg   = ln >> 4;         // k-group / C-row-group
    const int li   = ln & 15;         // A row (pixel) / B col (f)
    const int yloc = wv >> 1;         // 0..1: which output row
    const int xw   = (wv & 1) * 64;   // col base

    f32x4 acc[4][2];
    #pragma unroll
    for (int i = 0; i < 4; ++i) {
        acc[i][0] = (f32x4)0.0f;
        acc[i][1] = (f32x4)0.0f;
    }

    #pragma unroll
    for (int kh = 0; kh < 3; ++kh) {
        #pragma unroll
        for (int kw = 0; kw < 3; ++kw) {
            const int s = kh * 3 + kw;
            const bf16x8 b0 = *(const bf16x8*)(smem + wt_off(s * 4 + lg, li));
            const bf16x8 b1 = *(const bf16x8*)(smem + wt_off(s * 4 + lg, 16 + li));
            const int r = yloc + kh;
            // lds col = 1 + (pixel_col + kw - 1) = xw + tI*16 + li + kw
            const int colbase = xw + li + kw;
            #pragma unroll
            for (int tI = 0; tI < 4; ++tI) {
                const bf16x8 a = *(const bf16x8*)(smem + xs_off(lg, r, colbase + tI * 16));
                acc[tI][0] = __builtin_amdgcn_mfma_f32_16x16x32_bf16(a, b0, acc[tI][0], 0, 0, 0);
                acc[tI][1] = __builtin_amdgcn_mfma_f32_16x16x32_bf16(a, b1, acc[tI][1], 0, 0, 0);
            }
        }
    }

    // ---- epilogue: C layout col=lane&15 (f), row=(lane>>4)*4+reg (pixel)
    const float bias0 = pw[WSZ + li];
    const float bias1 = pw[WSZ + 16 + li];
    const int yo = y0 + yloc;
    float* __restrict__ ob = out + ((size_t)(b * HWD + yo)) * (HWD * FC);

    #pragma unroll
    for (int tI = 0; tI < 4; ++tI) {
        #pragma unroll
        for (int reg = 0; reg < 4; ++reg) {
            const int px = xw + tI * 16 + lg * 4 + reg;
            float* q = ob + (size_t)px * FC;
            q[li]      = acc[tI][0][reg] + bias0;
            q[16 + li] = acc[tI][1][reg] + bias1;
        }
    }
}

extern "C" void kernel_launch(void* const* d_in, const int* in_sizes, int n_in,
                              void* d_out, int out_size, void* d_ws, size_t ws_size,
                              hipStream_t stream)
{
    const float* x      = (const float*)d_in[0];
    const float* params = (const float*)d_in[1];
    float*       out    = (float*)d_out;

    dim3 grid(2048);   // 32 samples x 64 row-pairs
    dim3 block(256);
    hipLaunchKernelGGL(conv3x3_mfma, grid, block, 0, stream, x, params, out);
}